// Round 1
// 97.316 us; speedup vs baseline: 1.0105x; 1.0105x over previous
//
#include <hip/hip_runtime.h>
#include <hip/hip_fp16.h>

#define CELL 128
#define STEPS 20

typedef _Float16 half8_t __attribute__((ext_vector_type(8)));
typedef float    floatx4 __attribute__((ext_vector_type(4)));

// ---------------- workspace layout (written by prep, read by main) ----------
// WS_GX : [20][512] f32 gates_x with b_ih+b_hh folded, index t*512 + cell*4 + tau
// WS_WHH: [16][512] half8 W_hh fragments (uint4), g = tau*4+kc, m = main-thread id
// WS_FCW: [24*64] u32 packed half2 fc_W (same content as old s_fcw2)
// WS_FCB: [24] f32 fc_b
#define WS_GX    0
#define WS_WHH   40960
#define WS_FCW   (40960 + 131072)          // 172032
#define WS_FCB   (WS_FCW + 6144)           // 178176
#define WS_NEED  (WS_FCB + 96)             // 178272 bytes

__device__ __forceinline__ unsigned packf2(float x, float y) {
    typedef _Float16 h2 __attribute__((ext_vector_type(2)));
    h2 h = { (_Float16)x, (_Float16)y };
    return __builtin_bit_cast(unsigned, h);
}
__device__ __forceinline__ float fdot2u(unsigned a, unsigned b, float c) {
    typedef _Float16 h2 __attribute__((ext_vector_type(2)));
#if __has_builtin(__builtin_amdgcn_fdot2)
    return __builtin_amdgcn_fdot2(__builtin_bit_cast(h2, a), __builtin_bit_cast(h2, b), c, false);
#else
    h2 x = __builtin_bit_cast(h2, a), y = __builtin_bit_cast(h2, b);
    return fmaf((float)x[0], (float)y[0], fmaf((float)x[1], (float)y[1], c));
#endif
}
__device__ __forceinline__ float fastrcp(float x) {
#if __has_builtin(__builtin_amdgcn_rcpf)
    return __builtin_amdgcn_rcpf(x);
#else
    return 1.0f / x;
#endif
}
__device__ __forceinline__ float sig_rcp(float x)  { return fastrcp(1.0f + __expf(-x)); }
__device__ __forceinline__ float tanh_rcp(float x) { return fmaf(2.0f, fastrcp(1.0f + __expf(-2.0f * x)), -1.0f); }
__device__ __forceinline__ half8_t cvt8(const float* p) {
    const float4* p4 = (const float4*)p;
    float4 a = p4[0], b = p4[1];
    return half8_t{ (_Float16)a.x, (_Float16)a.y, (_Float16)a.z, (_Float16)a.w,
                    (_Float16)b.x, (_Float16)b.y, (_Float16)b.z, (_Float16)b.w };
}

// ============================================================================
// Kernel A — wide prep. Theory: timed iterations are cache-cold (256 MiB
// flush fills between dispatches), so the old mono kernel paid a single-CU
// cold HBM fetch of 535 KB. Spread that fetch over 161 CUs, fold phase 1
// (x @ W_ih^T + biases) into it in fp32, and emit W_hh as f16 fragments in
// the exact per-thread order the serial kernel consumes.
// ============================================================================
extern "C" __global__ void __launch_bounds__(256)
nas_prep_kernel(const int* __restrict__ net,
                const float* __restrict__ emb_start,
                const float* __restrict__ emb_keys,
                const float* __restrict__ fc_W,
                const float* __restrict__ fc_b,
                const float* __restrict__ W_ih,
                const float* __restrict__ W_hh,
                const float* __restrict__ b_ih,
                const float* __restrict__ b_hh,
                unsigned char* __restrict__ ws)
{
    const int b = blockIdx.x, tid = threadIdx.x;

    if (b < 128) {
        // ---- gates_x: blocks 0..127, 4 W_ih rows per block, 64 lanes/row ----
        __shared__ float sx[STEPS][CELL];
        for (int i = tid; i < STEPS * CELL; i += 256) {
            const int t = i >> 7, k = i & 127;
            sx[t][k] = (t == 0) ? emb_start[k]
                     : emb_keys[((((t - 1) & 3) * 6) + net[t - 1]) * CELL + k];
        }
        __syncthreads();
        const int row  = b * 4 + (tid >> 6);        // 0..511 = tau*128 + cell
        const int lane = tid & 63;
        const float2 w = ((const float2*)W_ih)[row * 64 + lane];
        const float bias = b_ih[row] + b_hh[row];
        const int tau = row >> 7, cell = row & 127;
        float* gx = (float*)(ws + WS_GX);
#pragma unroll
        for (int t = 0; t < STEPS; ++t) {
            const float2 xv = *(const float2*)&sx[t][lane * 2];
            float p = fmaf(w.x, xv.x, w.y * xv.y);
            p += __shfl_down(p, 32); p += __shfl_down(p, 16);
            p += __shfl_down(p, 8);  p += __shfl_down(p, 4);
            p += __shfl_down(p, 2);  p += __shfl_down(p, 1);
            if (lane == 0) gx[t * 512 + cell * 4 + tau] = p + bias;
        }
    } else if (b < 160) {
        // ---- W_hh f16 fragment pack: blocks 128..159, one frag per thread ----
        const int F   = (b - 128) * 256 + tid;      // 0..8191
        const int g   = F >> 9;                     // 0..15 = tau*4 + kc
        const int m   = F & 511;                    // main-kernel thread id
        const int tau = g >> 2, kc = g & 3;
        const int rr0 = ((m >> 6) << 4) + (m & 15); // wv*16 + lcol
        const int qd  = (m >> 4) & 3;
        const int k0  = kc * 32 + qd * 8;
        half8_t h8 = cvt8(W_hh + (tau * 128 + rr0) * CELL + k0);
        ((uint4*)(ws + WS_WHH))[g * 512 + m] = __builtin_bit_cast(uint4, h8);
    } else {
        // ---- fc pack: block 160 ----
        const float2* fw2 = (const float2*)fc_W;
        unsigned* fcw = (unsigned*)(ws + WS_FCW);
        for (int i = tid; i < 24 * 64; i += 256) {
            const float2 w = fw2[i];
            fcw[i] = packf2(w.x, w.y);
        }
        if (tid < 24) ((float*)(ws + WS_FCB))[tid] = fc_b[tid];
    }
}

// ============================================================================
// Kernel B — serial recurrence, structure identical to the proven mono loop:
// 1 barrier/step, no shuffles in the chain, heads in the MFMA shadow.
// Changes vs mono: no phase 1, no s_gx/s_xv2 LDS, frags loaded as coalesced
// uint4 (no cvt), gx register-double-buffered from global (prefetch in MFMA
// shadow), and gx folded into the MFMA C operand (acc[0] init) — removing
// the post-MFMA gx/bias adds from the serial chain.
// ============================================================================
extern "C" __global__ void __launch_bounds__(512, 1)
nas_policy_kernel(const unsigned char* __restrict__ ws,
                  float* __restrict__ out)
{
    const int t0   = threadIdx.x;
    const int wv   = t0 >> 6;
    const int lane = t0 & 63;
    const int quad = lane >> 4;
    const int lcol = lane & 15;
    const int rr0  = (wv << 4) + lcol;

    __shared__ __align__(16) _Float16 hbuf[2 * 128];
    __shared__ float llog[STEPS * 8];

    const float*    ws_gx  = (const float*)(ws + WS_GX);
    const uint4*    ws_whh = (const uint4*)(ws + WS_WHH);
    const unsigned* ws_fcw = (const unsigned*)(ws + WS_FCW);
    const float*    ws_fcb = (const float*)(ws + WS_FCB);

    // W_hh fragments: 16 coalesced uint4 loads (1 KB/wave/instr), L3-warm
    half8_t bf0[4], bf1[4], bf2[4], bf3[4];
#pragma unroll
    for (int kc = 0; kc < 4; ++kc) {
        bf0[kc] = __builtin_bit_cast(half8_t, ws_whh[(0 * 4 + kc) * 512 + t0]);
        bf1[kc] = __builtin_bit_cast(half8_t, ws_whh[(1 * 4 + kc) * 512 + t0]);
        bf2[kc] = __builtin_bit_cast(half8_t, ws_whh[(2 * 4 + kc) * 512 + t0]);
        bf3[kc] = __builtin_bit_cast(half8_t, ws_whh[(3 * 4 + kc) * 512 + t0]);
    }
    if (t0 < 128) hbuf[128 + t0] = (_Float16)0.0f;    // h(-1) = 0 (parity 1)
    floatx4 gx_cur = *(const floatx4*)&ws_gx[rr0 * 4];   // gx[t=0]
    float c = 0.0f;
    __syncthreads();

    for (int t = 0; t < STEPS; ++t) {
        const uint4* hp4 = (const uint4*)(hbuf + (((t + 1) & 1) << 7));  // h(t-1)
        const floatx4 gx = gx_cur;
        if (t + 1 < STEPS)            // prefetch next gx in the MFMA shadow
            gx_cur = *(const floatx4*)&ws_gx[(t + 1) * 512 + rr0 * 4];

        floatx4 a0a = { gx[0], 0, 0, 0 }, a0b = { 0, 0, 0, 0 };
        floatx4 a1a = { gx[1], 0, 0, 0 }, a1b = { 0, 0, 0, 0 };
        floatx4 a2a = { gx[2], 0, 0, 0 }, a2b = { 0, 0, 0, 0 };
        floatx4 a3a = { gx[3], 0, 0, 0 }, a3b = { 0, 0, 0, 0 };
        {
            uint4 u0 = hp4[(0 << 2) + quad], u1 = hp4[(1 << 2) + quad];
            uint4 u2 = hp4[(2 << 2) + quad], u3 = hp4[(3 << 2) + quad];
            half8_t f0 = __builtin_bit_cast(half8_t, u0), f1 = __builtin_bit_cast(half8_t, u1);
            half8_t f2 = __builtin_bit_cast(half8_t, u2), f3 = __builtin_bit_cast(half8_t, u3);
            a0a = __builtin_amdgcn_mfma_f32_16x16x32_f16(f0, bf0[0], a0a, 0, 0, 0);
            a1a = __builtin_amdgcn_mfma_f32_16x16x32_f16(f0, bf1[0], a1a, 0, 0, 0);
            a2a = __builtin_amdgcn_mfma_f32_16x16x32_f16(f0, bf2[0], a2a, 0, 0, 0);
            a3a = __builtin_amdgcn_mfma_f32_16x16x32_f16(f0, bf3[0], a3a, 0, 0, 0);
            a0b = __builtin_amdgcn_mfma_f32_16x16x32_f16(f1, bf0[1], a0b, 0, 0, 0);
            a1b = __builtin_amdgcn_mfma_f32_16x16x32_f16(f1, bf1[1], a1b, 0, 0, 0);
            a2b = __builtin_amdgcn_mfma_f32_16x16x32_f16(f1, bf2[1], a2b, 0, 0, 0);
            a3b = __builtin_amdgcn_mfma_f32_16x16x32_f16(f1, bf3[1], a3b, 0, 0, 0);
            a0a = __builtin_amdgcn_mfma_f32_16x16x32_f16(f2, bf0[2], a0a, 0, 0, 0);
            a1a = __builtin_amdgcn_mfma_f32_16x16x32_f16(f2, bf1[2], a1a, 0, 0, 0);
            a2a = __builtin_amdgcn_mfma_f32_16x16x32_f16(f2, bf2[2], a2a, 0, 0, 0);
            a3a = __builtin_amdgcn_mfma_f32_16x16x32_f16(f2, bf3[2], a3a, 0, 0, 0);
            a0b = __builtin_amdgcn_mfma_f32_16x16x32_f16(f3, bf0[3], a0b, 0, 0, 0);
            a1b = __builtin_amdgcn_mfma_f32_16x16x32_f16(f3, bf1[3], a1b, 0, 0, 0);
            a2b = __builtin_amdgcn_mfma_f32_16x16x32_f16(f3, bf2[3], a2b, 0, 0, 0);
            a3b = __builtin_amdgcn_mfma_f32_16x16x32_f16(f3, bf3[3], a3b, 0, 0, 0);
        }

        // heads of step t-1 on waves 0-5 quad 1, in the MFMA shadow
        if (t >= 1 && wv < 6 && quad == 1) {
            const int li = lcol;
            const int hg = ((t - 1) & 3) * 6 + wv;
            const unsigned* hb = (const unsigned*)(hbuf + (((t + 1) & 1) << 7));
            const uint4 wpv = *(const uint4*)(ws_fcw + hg * 64 + li * 4);
            float p = fdot2u(hb[li * 4],     wpv.x, 0.0f);
            p = fdot2u(hb[li * 4 + 1], wpv.y, p);
            p = fdot2u(hb[li * 4 + 2], wpv.z, p);
            p = fdot2u(hb[li * 4 + 3], wpv.w, p);
            p += __shfl_down(p, 8); p += __shfl_down(p, 4);
            p += __shfl_down(p, 2); p += __shfl_down(p, 1);
            if (li == 0) llog[(t - 1) * 8 + wv] = p + ws_fcb[hg];
        }

        // full elementwise on every lane (broadcast rows; gx already in acc)
        {
            float ig = sig_rcp (a0a[0] + a0b[0]);
            float fg = sig_rcp (a1a[0] + a1b[0]);
            float gg = tanh_rcp(a2a[0] + a2b[0]);
            float og = sig_rcp (a3a[0] + a3b[0]);
            c = fg * c + ig * gg;
            float h = og * tanh_rcp(c);
            if (quad == 0)
                hbuf[((t & 1) << 7) + rr0] = (_Float16)h;
        }

        __syncthreads();
    }

    // ======== epilogue: head(19) + all 20 softmaxes ========
    if (wv < 6 && quad == 1) {
        const int li = lcol;
        const int hg = (19 & 3) * 6 + wv;
        const unsigned* hb = (const unsigned*)(hbuf + 128);   // h(19), parity 1
        const uint4 wpv = *(const uint4*)(ws_fcw + hg * 64 + li * 4);
        float p = fdot2u(hb[li * 4],     wpv.x, 0.0f);
        p = fdot2u(hb[li * 4 + 1], wpv.y, p);
        p = fdot2u(hb[li * 4 + 2], wpv.z, p);
        p = fdot2u(hb[li * 4 + 3], wpv.w, p);
        p += __shfl_down(p, 8); p += __shfl_down(p, 4);
        p += __shfl_down(p, 2); p += __shfl_down(p, 1);
        if (li == 0) llog[19 * 8 + wv] = p + ws_fcb[hg];
    }
    __syncthreads();
    if (t0 < STEPS * 6) {
        const int s = t0 / 6, k = t0 - s * 6;
        const float* L = llog + s * 8;
        float l0 = L[0], l1 = L[1], l2 = L[2], l3 = L[3], l4 = L[4], l5 = L[5];
        float m = fmaxf(fmaxf(fmaxf(l0, l1), fmaxf(l2, l3)), fmaxf(l4, l5));
        float e0 = __expf(l0 - m), e1 = __expf(l1 - m), e2 = __expf(l2 - m);
        float e3 = __expf(l3 - m), e4 = __expf(l4 - m), e5 = __expf(l5 - m);
        float sum = ((e0 + e1) + (e2 + e3)) + (e4 + e5);
        float mine = (k == 0) ? e0 : (k == 1) ? e1 : (k == 2) ? e2
                   : (k == 3) ? e3 : (k == 4) ? e4 : e5;
        out[t0] = mine / sum;
    }
}

// ============================================================================
// Fallback: the proven mono kernel, used only if ws is too small.
// ============================================================================
extern "C" __global__ void __launch_bounds__(512, 1)
nas_policy_mono(const int* __restrict__ net,
                const float* __restrict__ emb_start,
                const float* __restrict__ emb_keys,
                const float* __restrict__ fc_W,
                const float* __restrict__ fc_b,
                const float* __restrict__ W_ih,
                const float* __restrict__ W_hh,
                const float* __restrict__ b_ih,
                const float* __restrict__ b_hh,
                float* __restrict__ out)
{
    const int t0   = threadIdx.x;
    const int wv   = t0 >> 6;
    const int lane = t0 & 63;
    const int quad = lane >> 4;
    const int lcol = lane & 15;

    __shared__ __align__(16) unsigned  s_xv2[32 * 68];
    __shared__ __align__(16) float     s_gx[STEPS * 512];
    __shared__ __align__(16) _Float16  hbuf[2 * 128];
    __shared__ unsigned s_fcw2[24 * 64];
    __shared__ float    s_fcb[24];
    __shared__ float    llog[STEPS * 8];

    for (int i = t0; i < STEPS * 64; i += 512) {
        const int m = i >> 6, j = i & 63;
        const float2* src = (m == 0) ? (const float2*)emb_start
            : (const float2*)(emb_keys + ((((m - 1) & 3) * 6) + net[m - 1]) * CELL);
        float2 v = src[j];
        s_xv2[m * 68 + j] = packf2(v.x, v.y);
    }
    {
        const float2* fw2 = (const float2*)fc_W;
        for (int i = t0; i < 24 * 64; i += 512) { float2 w = fw2[i]; s_fcw2[i] = packf2(w.x, w.y); }
    }
    if (t0 < 24)  s_fcb[t0] = fc_b[t0];
    if (t0 < 128) hbuf[128 + t0] = (_Float16)0.0f;

    const int rr0 = (wv << 4) + lcol;
    float biasx[4];
#pragma unroll
    for (int tau = 0; tau < 4; ++tau) {
        const int r = tau * 128 + rr0;
        biasx[tau] = b_ih[r] + b_hh[r];
    }

    __syncthreads();

    {
        half8_t bw[4][4];
#pragma unroll
        for (int kc = 0; kc < 4; ++kc) {
            const int k0 = kc * 32 + quad * 8;
#pragma unroll
            for (int tau = 0; tau < 4; ++tau)
                bw[kc][tau] = cvt8(W_ih + (tau * 128 + rr0) * CELL + k0);
        }
        floatx4 ax0[4] = { {0,0,0,0}, {0,0,0,0}, {0,0,0,0}, {0,0,0,0} };
        floatx4 ax1[4] = { {0,0,0,0}, {0,0,0,0}, {0,0,0,0}, {0,0,0,0} };
#pragma unroll
        for (int kc = 0; kc < 4; ++kc) {
            uint4 u0 = *(const uint4*)&s_xv2[lcol * 68 + kc * 16 + quad * 4];
            uint4 u1 = *(const uint4*)&s_xv2[(16 + lcol) * 68 + kc * 16 + quad * 4];
            half8_t a0f = __builtin_bit_cast(half8_t, u0);
            half8_t a1f = __builtin_bit_cast(half8_t, u1);
#pragma unroll
            for (int tau = 0; tau < 4; ++tau) {
                ax0[tau] = __builtin_amdgcn_mfma_f32_16x16x32_f16(a0f, bw[kc][tau], ax0[tau], 0, 0, 0);
                ax1[tau] = __builtin_amdgcn_mfma_f32_16x16x32_f16(a1f, bw[kc][tau], ax1[tau], 0, 0, 0);
            }
        }
#pragma unroll
        for (int tau = 0; tau < 4; ++tau) {
#pragma unroll
            for (int reg = 0; reg < 4; ++reg)
                s_gx[(quad * 4 + reg) * 512 + rr0 * 4 + tau] = ax0[tau][reg] + biasx[tau];
            if (quad == 0) {
#pragma unroll
                for (int reg = 0; reg < 4; ++reg)
                    s_gx[(16 + reg) * 512 + rr0 * 4 + tau] = ax1[tau][reg] + biasx[tau];
            }
        }
    }

    half8_t bf0[4], bf1[4], bf2[4], bf3[4];
#pragma unroll
    for (int kc = 0; kc < 4; ++kc) {
        const int k0 = kc * 32 + quad * 8;
        bf0[kc] = cvt8(W_hh + (0 * 128 + rr0) * CELL + k0);
        bf1[kc] = cvt8(W_hh + (1 * 128 + rr0) * CELL + k0);
        bf2[kc] = cvt8(W_hh + (2 * 128 + rr0) * CELL + k0);
        bf3[kc] = cvt8(W_hh + (3 * 128 + rr0) * CELL + k0);
    }

    float c = 0.0f;
    __syncthreads();

    for (int t = 0; t < STEPS; ++t) {
        const uint4* hp4 = (const uint4*)(hbuf + (((t + 1) & 1) << 7));
        floatx4 gx = *(const floatx4*)&s_gx[t * 512 + rr0 * 4];
        floatx4 a0a = {0,0,0,0}, a0b = {0,0,0,0}, a1a = {0,0,0,0}, a1b = {0,0,0,0};
        floatx4 a2a = {0,0,0,0}, a2b = {0,0,0,0}, a3a = {0,0,0,0}, a3b = {0,0,0,0};
        {
            uint4 u0 = hp4[(0 << 2) + quad], u1 = hp4[(1 << 2) + quad];
            uint4 u2 = hp4[(2 << 2) + quad], u3 = hp4[(3 << 2) + quad];
            half8_t f0 = __builtin_bit_cast(half8_t, u0), f1 = __builtin_bit_cast(half8_t, u1);
            half8_t f2 = __builtin_bit_cast(half8_t, u2), f3 = __builtin_bit_cast(half8_t, u3);
            a0a = __builtin_amdgcn_mfma_f32_16x16x32_f16(f0, bf0[0], a0a, 0, 0, 0);
            a1a = __builtin_amdgcn_mfma_f32_16x16x32_f16(f0, bf1[0], a1a, 0, 0, 0);
            a2a = __builtin_amdgcn_mfma_f32_16x16x32_f16(f0, bf2[0], a2a, 0, 0, 0);
            a3a = __builtin_amdgcn_mfma_f32_16x16x32_f16(f0, bf3[0], a3a, 0, 0, 0);
            a0b = __builtin_amdgcn_mfma_f32_16x16x32_f16(f1, bf0[1], a0b, 0, 0, 0);
            a1b = __builtin_amdgcn_mfma_f32_16x16x32_f16(f1, bf1[1], a1b, 0, 0, 0);
            a2b = __builtin_amdgcn_mfma_f32_16x16x32_f16(f1, bf2[1], a2b, 0, 0, 0);
            a3b = __builtin_amdgcn_mfma_f32_16x16x32_f16(f1, bf3[1], a3b, 0, 0, 0);
            a0a = __builtin_amdgcn_mfma_f32_16x16x32_f16(f2, bf0[2], a0a, 0, 0, 0);
            a1a = __builtin_amdgcn_mfma_f32_16x16x32_f16(f2, bf1[2], a1a, 0, 0, 0);
            a2a = __builtin_amdgcn_mfma_f32_16x16x32_f16(f2, bf2[2], a2a, 0, 0, 0);
            a3a = __builtin_amdgcn_mfma_f32_16x16x32_f16(f2, bf3[2], a3a, 0, 0, 0);
            a0b = __builtin_amdgcn_mfma_f32_16x16x32_f16(f3, bf0[3], a0b, 0, 0, 0);
            a1b = __builtin_amdgcn_mfma_f32_16x16x32_f16(f3, bf1[3], a1b, 0, 0, 0);
            a2b = __builtin_amdgcn_mfma_f32_16x16x32_f16(f3, bf2[3], a2b, 0, 0, 0);
            a3b = __builtin_amdgcn_mfma_f32_16x16x32_f16(f3, bf3[3], a3b, 0, 0, 0);
        }

        if (t >= 1 && wv < 6 && quad == 1) {
            const int li = lcol;
            const int hg = ((t - 1) & 3) * 6 + wv;
            const unsigned* hb = (const unsigned*)(hbuf + (((t + 1) & 1) << 7));
            const unsigned* wp = s_fcw2 + hg * 64 + li * 4;
            float p = fdot2u(hb[li * 4],     wp[0], 0.0f);
            p = fdot2u(hb[li * 4 + 1], wp[1], p);
            p = fdot2u(hb[li * 4 + 2], wp[2], p);
            p = fdot2u(hb[li * 4 + 3], wp[3], p);
            p += __shfl_down(p, 8); p += __shfl_down(p, 4);
            p += __shfl_down(p, 2); p += __shfl_down(p, 1);
            if (li == 0) llog[(t - 1) * 8 + wv] = p + s_fcb[hg];
        }

        {
            float ig = sig_rcp (a0a[0] + a0b[0] + gx[0]);
            float fg = sig_rcp (a1a[0] + a1b[0] + gx[1]);
            float gg = tanh_rcp(a2a[0] + a2b[0] + gx[2]);
            float og = sig_rcp (a3a[0] + a3b[0] + gx[3]);
            c = fg * c + ig * gg;
            float h = og * tanh_rcp(c);
            if (quad == 0)
                hbuf[((t & 1) << 7) + rr0] = (_Float16)h;
        }

        __syncthreads();
    }

    if (wv < 6 && quad == 1) {
        const int li = lcol;
        const int hg = (19 & 3) * 6 + wv;
        const unsigned* hb = (const unsigned*)(hbuf + 128);
        const unsigned* wp = s_fcw2 + hg * 64 + li * 4;
        float p = fdot2u(hb[li * 4],     wp[0], 0.0f);
        p = fdot2u(hb[li * 4 + 1], wp[1], p);
        p = fdot2u(hb[li * 4 + 2], wp[2], p);
        p = fdot2u(hb[li * 4 + 3], wp[3], p);
        p += __shfl_down(p, 8); p += __shfl_down(p, 4);
        p += __shfl_down(p, 2); p += __shfl_down(p, 1);
        if (li == 0) llog[19 * 8 + wv] = p + s_fcb[hg];
    }
    __syncthreads();
    if (t0 < STEPS * 6) {
        const int s = t0 / 6, k = t0 - s * 6;
        const float* L = llog + s * 8;
        float l0 = L[0], l1 = L[1], l2 = L[2], l3 = L[3], l4 = L[4], l5 = L[5];
        float m = fmaxf(fmaxf(fmaxf(l0, l1), fmaxf(l2, l3)), fmaxf(l4, l5));
        float e0 = __expf(l0 - m), e1 = __expf(l1 - m), e2 = __expf(l2 - m);
        float e3 = __expf(l3 - m), e4 = __expf(l4 - m), e5 = __expf(l5 - m);
        float sum = ((e0 + e1) + (e2 + e3)) + (e4 + e5);
        float mine = (k == 0) ? e0 : (k == 1) ? e1 : (k == 2) ? e2
                   : (k == 3) ? e3 : (k == 4) ? e4 : e5;
        out[t0] = mine / sum;
    }
}

extern "C" void kernel_launch(void* const* d_in, const int* in_sizes, int n_in,
                              void* d_out, int out_size, void* d_ws, size_t ws_size,
                              hipStream_t stream) {
    (void)in_sizes; (void)n_in; (void)out_size;
    const int*   net       = (const int*)d_in[0];
    // d_in[1] = reward, unused in forward
    const float* emb_start = (const float*)d_in[2];
    const float* emb_keys  = (const float*)d_in[3];
    const float* fc_W      = (const float*)d_in[4];
    const float* fc_b      = (const float*)d_in[5];
    const float* W_ih      = (const float*)d_in[6];
    const float* W_hh      = (const float*)d_in[7];
    const float* b_ih      = (const float*)d_in[8];
    const float* b_hh      = (const float*)d_in[9];
    float*       out       = (float*)d_out;

    if (d_ws != nullptr && ws_size >= (size_t)WS_NEED) {
        unsigned char* ws = (unsigned char*)d_ws;
        hipLaunchKernelGGL(nas_prep_kernel, dim3(161), dim3(256), 0, stream,
                           net, emb_start, emb_keys, fc_W, fc_b,
                           W_ih, W_hh, b_ih, b_hh, ws);
        hipLaunchKernelGGL(nas_policy_kernel, dim3(1), dim3(512), 0, stream,
                           (const unsigned char*)ws, out);
    } else {
        hipLaunchKernelGGL(nas_policy_mono, dim3(1), dim3(512), 0, stream,
                           net, emb_start, emb_keys, fc_W, fc_b,
                           W_ih, W_hh, b_ih, b_hh, out);
    }
}